// Round 1
// baseline (389.871 us; speedup 1.0000x reference)
//
#include <hip/hip_runtime.h>
#include <hip/hip_bf16.h>
#include <hip/hip_cooperative_groups.h>
#include <math.h>

namespace cg = cooperative_groups;

// ---------------------------------------------------------------------------
// B=1024, D_DATA=16384, D_LAT=256, N_GRID=256. Inputs f32.
// d_out = f32 slots; harness reads high u16 of each slot as bf16 -> store
// (float)__float2bfloat16(v) (proven R6).
//
// Structure (2 launches total):
//   losses_kernel : 1024 blocks x 512 threads (32 waves/CU) -> recon/kl
//                   partials + row norms sq.
//   mst_kernel    : cooperative, 256 blocks x 256 threads. dist tile GEMM ->
//                   grid.sync -> Boruvka rounds (comp kept in LDS per block,
//                   phase B redundant per block => ONE grid.sync/round via
//                   double-buffered minedge), early exit at 1 component,
//                   block 0 tail: silhouette + final output.
//
// ws layout (floats) — peak 4,227,072 B, identical to proven layout:
//   [0..1023]     recon partials   [1024..2047] kl partials
//   [2048..3071]  sq
//   [4096..8191]  minedge (u64[2][1024], byte 16384, 8-aligned)
//   [8192..]      dist 1024x1024 (4 MB)
// ---------------------------------------------------------------------------

#define NBLK 1024

__global__ __launch_bounds__(512) void losses_kernel(const float4* __restrict__ rx,
                                                     const float4* __restrict__ x,
                                                     const float4* __restrict__ mu,
                                                     const float4* __restrict__ lv,
                                                     const float* __restrict__ z,
                                                     float* __restrict__ partials,
                                                     float* __restrict__ sq) {
  const int t = threadIdx.x;
  const int gid = blockIdx.x * 512 + t;
  const int gstride = NBLK * 512;

  float rs = 0.f;
  for (int i = gid; i < 4194304; i += gstride) {
    float4 a = rx[i], b = x[i];
    float dx = a.x - b.x, dy = a.y - b.y, dz = a.z - b.z, dw = a.w - b.w;
    rs += dx * dx + dy * dy + dz * dz + dw * dw;
  }
  float ks = 0.f;
  for (int i = gid; i < 65536; i += gstride) {
    float4 m = mu[i], l = lv[i];
    ks += 1.f + l.x - m.x * m.x - __expf(l.x);
    ks += 1.f + l.y - m.y * m.y - __expf(l.y);
    ks += 1.f + l.z - m.z * m.z - __expf(l.z);
    ks += 1.f + l.w - m.w * m.w - __expf(l.w);
  }
#pragma unroll
  for (int off = 32; off; off >>= 1) {
    rs += __shfl_xor(rs, off);
    ks += __shfl_xor(ks, off);
  }
  __shared__ float red[16];
  if ((t & 63) == 0) { red[t >> 6] = rs; red[8 + (t >> 6)] = ks; }
  __syncthreads();
  if (t == 0) {
    float a = 0.f, b = 0.f;
#pragma unroll
    for (int w = 0; w < 8; ++w) { a += red[w]; b += red[8 + w]; }
    partials[blockIdx.x] = a;
    partials[NBLK + blockIdx.x] = b;
  }
  if (blockIdx.x < 128) {
    const int lane = t & 63;
    const int row = blockIdx.x * 8 + (t >> 6);
    float4 v = ((const float4*)(z + row * 256))[lane];
    float s = v.x * v.x + v.y * v.y + v.z * v.z + v.w * v.w;
#pragma unroll
    for (int off = 32; off; off >>= 1) s += __shfl_xor(s, off);
    if (lane == 0) sq[row] = s;
  }
}

__global__ __launch_bounds__(256) void mst_kernel(const float* __restrict__ z,
                                                  const float* __restrict__ sq,
                                                  float* __restrict__ dist,
                                                  unsigned long long* __restrict__ minedge,
                                                  const float* __restrict__ partials,
                                                  float* __restrict__ out) {
  cg::grid_group grid = cg::this_grid();
  __shared__ float A[64][68];
  __shared__ float Bs[64][68];
  __shared__ int scomp[1024];
  __shared__ int pnew[1024];
  __shared__ unsigned long long cmin[1024];
  __shared__ float sdeaths[1023];
  __shared__ int sred[2];     // [0] ncomp scratch, [1] death counter (block 0)
  __shared__ float redf[12];

  const int t = threadIdx.x;
  const int bid = blockIdx.x;

  // ---------------- dist tile (one 64x64 tile per block) ----------------
  {
    const int i0 = (bid >> 4) * 64, j0 = (bid & 15) * 64;
    const int tx = t & 15, ty = t >> 4;
    float acc[4][4] = {};
    for (int k0 = 0; k0 < 256; k0 += 64) {
      __syncthreads();
#pragma unroll
      for (int it = 0; it < 4; ++it) {
        int lin = it * 256 + t;
        int row = lin >> 4, q = lin & 15;
        *(float4*)&A[row][q * 4]  = *(const float4*)(z + (i0 + row) * 256 + k0 + q * 4);
        *(float4*)&Bs[row][q * 4] = *(const float4*)(z + (j0 + row) * 256 + k0 + q * 4);
      }
      __syncthreads();
#pragma unroll 4
      for (int k = 0; k < 64; k += 4) {
        float4 av[4], bv[4];
#pragma unroll
        for (int rr = 0; rr < 4; ++rr) av[rr] = *(const float4*)&A[ty + 16 * rr][k];
#pragma unroll
        for (int cc = 0; cc < 4; ++cc) bv[cc] = *(const float4*)&Bs[tx + 16 * cc][k];
#pragma unroll
        for (int rr = 0; rr < 4; ++rr)
#pragma unroll
          for (int cc = 0; cc < 4; ++cc) {
            acc[rr][cc] += av[rr].x * bv[cc].x;
            acc[rr][cc] += av[rr].y * bv[cc].y;
            acc[rr][cc] += av[rr].z * bv[cc].z;
            acc[rr][cc] += av[rr].w * bv[cc].w;
          }
      }
    }
#pragma unroll
    for (int rr = 0; rr < 4; ++rr) {
      int i = i0 + ty + 16 * rr;
      float sqi = sq[i];
#pragma unroll
      for (int cc = 0; cc < 4; ++cc) {
        int j = j0 + tx + 16 * cc;
        float d2 = sqi + sq[j] - 2.f * acc[rr][cc];
        dist[i * 1024 + j] = sqrtf(fmaxf(d2, 0.f) + 1e-12f);
      }
    }
  }

  for (int v = t; v < 1024; v += 256) scomp[v] = v;
  if (t == 0) sred[1] = 0;
  __threadfence();
  grid.sync();   // dist complete grid-wide

  const int lane = t & 63;
  const int wv = t >> 6;

  for (int r = 0; r < 10; ++r) {
    // ---- phase A: min outgoing edge, one row per wave ----
    unsigned long long* me = minedge + ((r & 1) << 10);   // double buffer
    const int i = bid * 4 + wv;
    const int ci = scomp[i];
    const float* row = dist + i * 1024;
    unsigned long long best = ~0ull;
#pragma unroll
    for (int k = 0; k < 4; ++k) {
      const int j0 = lane * 4 + k * 256;
      const float4 d4 = *(const float4*)(row + j0);
      const int4 c4 = *(const int4*)(&scomp[j0]);
      const float dv[4] = {d4.x, d4.y, d4.z, d4.w};
      const int cv[4] = {c4.x, c4.y, c4.z, c4.w};
#pragma unroll
      for (int c = 0; c < 4; ++c) {
        if (cv[c] != ci) {
          const int j = j0 + c;
          const int lo = i < j ? i : j;
          const int hi = i + j - lo;
          const unsigned long long key =
              ((unsigned long long)__float_as_uint(dv[c]) << 32)
            | (unsigned long long)((lo << 10) | hi);
          if (key < best) best = key;
        }
      }
    }
#pragma unroll
    for (int off = 32; off; off >>= 1) {
      const unsigned int blo = __shfl_xor((unsigned int)best, off);
      const unsigned int bhi = __shfl_xor((unsigned int)(best >> 32), off);
      const unsigned long long o = ((unsigned long long)bhi << 32) | blo;
      if (o < best) best = o;
    }
    if (lane == 0) me[i] = best;
    __threadfence();
    grid.sync();   // minedge visible grid-wide

    // ---- phase B: redundant per block (deterministic) ----
    for (int v = t; v < 1024; v += 256) cmin[v] = ~0ull;
    __syncthreads();
    for (int v = t; v < 1024; v += 256) {
      const unsigned long long e = me[v];
      if (e != ~0ull) atomicMin(&cmin[scomp[v]], e);
    }
    __syncthreads();
    for (int v = t; v < 1024; v += 256) {
      int parent = scomp[v];
      if (parent == v) {                      // root
        const unsigned long long key = cmin[v];
        if (key != ~0ull) {
          const int lo = (int)((key >> 10) & 1023), hi = (int)(key & 1023);
          const int clo = scomp[lo], chi = scomp[hi];
          const int other = (clo == v) ? chi : clo;
          const bool mutual = (cmin[other] == key);
          if (bid == 0 && (!mutual || v < other)) {   // record once, block 0 only
            const int pos = atomicAdd(&sred[1], 1);
            sdeaths[pos] = __uint_as_float((unsigned int)(key >> 32));
          }
          parent = (mutual && v < other) ? v : other;
        }
      }
      pnew[v] = parent;
    }
    __syncthreads();
    // two pointer-doubling passes, then per-thread root walk
#pragma unroll
    for (int it = 0; it < 2; ++it) {
      int q0 = pnew[pnew[t]];
      int q1 = pnew[pnew[t + 256]];
      int q2 = pnew[pnew[t + 512]];
      int q3 = pnew[pnew[t + 768]];
      __syncthreads();
      pnew[t] = q0; pnew[t + 256] = q1; pnew[t + 512] = q2; pnew[t + 768] = q3;
      __syncthreads();
    }
    if (t == 0) sred[0] = 0;
    __syncthreads();
    int nroots = 0;
#pragma unroll
    for (int q = 0; q < 4; ++q) {
      const int v = t + q * 256;
      int p = pnew[v];
      while (p != pnew[p]) p = pnew[p];
      scomp[v] = p;
      if (p == v) ++nroots;
    }
    atomicAdd(&sred[0], nroots);
    __syncthreads();
    if (sred[0] == 1) break;   // uniform across grid -> sync counts match
  }

  // ---------------- tail: silhouette + final (block 0 only) ----------------
  if (bid != 0) return;
  float lmax = 0.f, lsum = 0.f;
  for (int v = t; v < 1023; v += 256) {
    const float d = sdeaths[v];
    lmax = fmaxf(lmax, d);
    lsum += d;
  }
#pragma unroll
  for (int off = 32; off; off >>= 1) {
    lmax = fmaxf(lmax, __shfl_xor(lmax, off));
    lsum += __shfl_xor(lsum, off);
  }
  if ((t & 63) == 0) { redf[t >> 6] = lmax; redf[4 + (t >> 6)] = lsum; }
  __syncthreads();
  const float tmax = fmaxf(fmaxf(redf[0], redf[1]), fmaxf(redf[2], redf[3]));
  const float wsum = redf[4] + redf[5] + redf[6] + redf[7];
  const float tt = (float)t * (1.0f / 255.0f) * tmax;
  float acc = 0.f;
  for (int j = 0; j < 1023; ++j) {
    const float dj = sdeaths[j];
    acc += dj * fmaxf(fminf(tt, dj - tt), 0.f);
  }
  float phi = acc / (wsum + 1e-12f);
  float rs = 0.f, ks = 0.f;
  for (int v = t; v < 1024; v += 256) { rs += partials[v]; ks += partials[1024 + v]; }
#pragma unroll
  for (int off = 32; off; off >>= 1) {
    phi += __shfl_xor(phi, off);
    rs += __shfl_xor(rs, off);
    ks += __shfl_xor(ks, off);
  }
  __syncthreads();
  if ((t & 63) == 0) { redf[t >> 6] = phi; redf[4 + (t >> 6)] = rs; redf[8 + (t >> 6)] = ks; }
  __syncthreads();
  if (t == 0) {
    const float topo = (redf[0] + redf[1] + redf[2] + redf[3]) * (1.f / 256.f);
    const float recon = (redf[4] + redf[5] + redf[6] + redf[7]) * (1.f / 16777216.f);
    const float kl = -0.5f * (redf[8] + redf[9] + redf[10] + redf[11]) * (1.f / 262144.f);
    const float total = recon + 0.1f * kl + 0.5f * topo;
    out[0] = (float)__float2bfloat16(total);
    out[1] = (float)__float2bfloat16(recon);
    out[2] = (float)__float2bfloat16(kl);
    out[3] = (float)__float2bfloat16(topo);
  }
}

extern "C" void kernel_launch(void* const* d_in, const int* in_sizes, int n_in,
                              void* d_out, int out_size, void* d_ws, size_t ws_size,
                              hipStream_t stream) {
  const float* rx = (const float*)d_in[0];
  const float* x  = (const float*)d_in[1];
  const float* mu = (const float*)d_in[2];
  const float* lv = (const float*)d_in[3];
  const float* z  = (const float*)d_in[4];

  float* wsf = (float*)d_ws;
  float* partials = wsf;                                   // [0..2047]
  float* sq       = wsf + 2048;                            // [2048..3071]
  unsigned long long* minedge = (unsigned long long*)(wsf + 4096); // u64[2][1024]
  float* dist     = wsf + 8192;                            // 4 MB
  float* out      = (float*)d_out;

  losses_kernel<<<NBLK, 512, 0, stream>>>((const float4*)rx, (const float4*)x,
                                          (const float4*)mu, (const float4*)lv,
                                          z, partials, sq);

  void* args[6];
  args[0] = (void*)&z;
  args[1] = (void*)&sq;
  args[2] = (void*)&dist;
  args[3] = (void*)&minedge;
  args[4] = (void*)&partials;
  args[5] = (void*)&out;
  hipLaunchCooperativeKernel((const void*)mst_kernel, dim3(256), dim3(256),
                             args, 0, stream);
}

// Round 2
// 270.757 us; speedup vs baseline: 1.4399x; 1.4399x over previous
//
#include <hip/hip_runtime.h>
#include <hip/hip_bf16.h>
#include <math.h>

// ---------------------------------------------------------------------------
// B=1024, D_DATA=16384, D_LAT=256, N_GRID=256. Inputs f32.
// d_out = f32 slots; harness reads high u16 of each slot as bf16 -> store
// (float)__float2bfloat16(v) (proven R6).
//
// Structure (12 launches, NO cooperative groups — R1 showed grid.sync costs
// ~25-30us each on 256 blocks/8 XCDs; kernel boundaries are the cheap sync):
//   losses_kernel   : 1024x512, recon/kl partials + row norms sq + ctrl init.
//   dist_kernel     : 256x256, dist tiles + FUSED Boruvka round-1 phase A
//                     (in-register row mins -> global atomicMin cmin_g) +
//                     last-arriving block runs phase B (identity comp).
//   round_kernel x9 : rounds 2..10. Phase A (wave per row, comp in LDS,
//                     atomicMin -> cmin_g) + last block runs phase B.
//                     Early-exit when ncomp==1 (launch cost only).
//   sil_final_kernel: 1x1024, silhouette (4-way split tent loop) + final.
//
// Cross-block comms: device-scope u64 atomics on cmin_g (atomicMin write,
// atomicExch consume+reset) — coherent at LLC, no L2 staleness risk.
// All other producer->consumer edges cross kernel boundaries.
//
// ws layout (floats) — peak 4,227,072 B:
//   [0..2047]    partials (recon | kl)
//   [2048..3071] sq
//   [3072..]     ctrl int[32]: [0]=cnt [1]=ncomp [8..23]=done_ctr
//   [3104..4126] deaths (1023)
//   [4160..6207] cmin_g u64[1024] (byte 16640, 8-aligned)
//   [6208..7231] comp int[1024]
//   [8192..]     dist 1024x1024 (4 MB)
// ---------------------------------------------------------------------------

#define NBLK 1024

__global__ __launch_bounds__(512) void losses_kernel(const float4* __restrict__ rx,
                                                     const float4* __restrict__ x,
                                                     const float4* __restrict__ mu,
                                                     const float4* __restrict__ lv,
                                                     const float* __restrict__ z,
                                                     float* __restrict__ partials,
                                                     float* __restrict__ sq,
                                                     int* __restrict__ ctrl,
                                                     unsigned long long* __restrict__ cmin_g) {
  const int t = threadIdx.x;
  if (blockIdx.x == 0) {               // init MST control state for this iter
    if (t < 16) ctrl[8 + t] = 0;
    if (t == 0) { ctrl[0] = 0; ctrl[1] = 1024; }
    for (int v = t; v < 1024; v += 512) cmin_g[v] = ~0ull;
  }
  const int gid = blockIdx.x * 512 + t;
  const int gstride = NBLK * 512;

  float rs = 0.f;
  for (int i = gid; i < 4194304; i += gstride) {
    float4 a = rx[i], b = x[i];
    float dx = a.x - b.x, dy = a.y - b.y, dz = a.z - b.z, dw = a.w - b.w;
    rs += dx * dx + dy * dy + dz * dz + dw * dw;
  }
  float ks = 0.f;
  for (int i = gid; i < 65536; i += gstride) {
    float4 m = mu[i], l = lv[i];
    ks += 1.f + l.x - m.x * m.x - __expf(l.x);
    ks += 1.f + l.y - m.y * m.y - __expf(l.y);
    ks += 1.f + l.z - m.z * m.z - __expf(l.z);
    ks += 1.f + l.w - m.w * m.w - __expf(l.w);
  }
#pragma unroll
  for (int off = 32; off; off >>= 1) {
    rs += __shfl_xor(rs, off);
    ks += __shfl_xor(ks, off);
  }
  __shared__ float red[16];
  if ((t & 63) == 0) { red[t >> 6] = rs; red[8 + (t >> 6)] = ks; }
  __syncthreads();
  if (t == 0) {
    float a = 0.f, b = 0.f;
#pragma unroll
    for (int w = 0; w < 8; ++w) { a += red[w]; b += red[8 + w]; }
    partials[blockIdx.x] = a;
    partials[NBLK + blockIdx.x] = b;
  }
  if (blockIdx.x < 128) {
    const int lane = t & 63;
    const int row = blockIdx.x * 8 + (t >> 6);
    float4 v = ((const float4*)(z + row * 256))[lane];
    float s = v.x * v.x + v.y * v.y + v.z * v.z + v.w * v.w;
#pragma unroll
    for (int off = 32; off; off >>= 1) s += __shfl_xor(s, off);
    if (lane == 0) sq[row] = s;
  }
}

// Shared phase B: consume cmin_g (atomicExch read+reset), merge components,
// record deaths, pointer-double + root-walk, write comp/ncomp. 256 threads.
// scomp must hold the CURRENT component ids (synced before call).
__device__ __forceinline__ void phase_b(int* scomp, unsigned long long* cmin_l,
                                        int* pnew, int* sred,
                                        unsigned long long* __restrict__ cmin_g,
                                        int* __restrict__ comp_g,
                                        float* __restrict__ deaths,
                                        int* __restrict__ cnt,
                                        int* __restrict__ ncomp) {
  const int t = threadIdx.x;
  for (int v = t; v < 1024; v += 256) cmin_l[v] = atomicExch(&cmin_g[v], ~0ull);
  if (t == 0) sred[0] = 0;
  __syncthreads();
  for (int v = t; v < 1024; v += 256) {
    int parent = scomp[v];
    if (parent == v) {                         // root
      const unsigned long long key = cmin_l[v];
      if (key != ~0ull) {
        const int lo = (int)((key >> 10) & 1023), hi = (int)(key & 1023);
        const int clo = scomp[lo], chi = scomp[hi];
        const int other = (clo == v) ? chi : clo;
        const bool mutual = (cmin_l[other] == key);
        if (!mutual || v < other) {            // dedupe mutual pair
          const int pos = atomicAdd(cnt, 1);
          deaths[pos] = __uint_as_float((unsigned int)(key >> 32));
        }
        parent = (mutual && v < other) ? v : other;
      }
    }
    pnew[v] = parent;
  }
  __syncthreads();
#pragma unroll
  for (int it = 0; it < 2; ++it) {
    int q0 = pnew[pnew[t]];
    int q1 = pnew[pnew[t + 256]];
    int q2 = pnew[pnew[t + 512]];
    int q3 = pnew[pnew[t + 768]];
    __syncthreads();
    pnew[t] = q0; pnew[t + 256] = q1; pnew[t + 512] = q2; pnew[t + 768] = q3;
    __syncthreads();
  }
  int nroots = 0;
#pragma unroll
  for (int q = 0; q < 4; ++q) {
    const int v = t + q * 256;
    int p = pnew[v];
    while (p != pnew[p]) p = pnew[p];
    comp_g[v] = p;
    if (p == v) ++nroots;
  }
  atomicAdd(&sred[0], nroots);
  __syncthreads();
  if (t == 0) *ncomp = sred[0];
}

__global__ __launch_bounds__(256) void dist_kernel(const float* __restrict__ z,
                                                   const float* __restrict__ sq,
                                                   float* __restrict__ dist,
                                                   int* __restrict__ ctrl,
                                                   unsigned long long* __restrict__ cmin_g,
                                                   int* __restrict__ comp_g,
                                                   float* __restrict__ deaths) {
  __shared__ float A[64][68];
  __shared__ float Bs[64][68];
  __shared__ int scomp[1024];
  __shared__ unsigned long long cmin_l[1024];
  __shared__ int pnew[1024];
  __shared__ int sred[2];
  const int i0 = (blockIdx.x >> 4) * 64, j0 = (blockIdx.x & 15) * 64;
  const int t = threadIdx.x;
  const int tx = t & 15;
  const int ty = t >> 4;
  float acc[4][4] = {};
  for (int k0 = 0; k0 < 256; k0 += 64) {
    __syncthreads();
#pragma unroll
    for (int it = 0; it < 4; ++it) {
      int lin = it * 256 + t;
      int row = lin >> 4, q = lin & 15;
      *(float4*)&A[row][q * 4]  = *(const float4*)(z + (i0 + row) * 256 + k0 + q * 4);
      *(float4*)&Bs[row][q * 4] = *(const float4*)(z + (j0 + row) * 256 + k0 + q * 4);
    }
    __syncthreads();
#pragma unroll 4
    for (int k = 0; k < 64; k += 4) {
      float4 av[4], bv[4];
#pragma unroll
      for (int rr = 0; rr < 4; ++rr) av[rr] = *(const float4*)&A[ty + 16 * rr][k];
#pragma unroll
      for (int cc = 0; cc < 4; ++cc) bv[cc] = *(const float4*)&Bs[tx + 16 * cc][k];
#pragma unroll
      for (int rr = 0; rr < 4; ++rr)
#pragma unroll
        for (int cc = 0; cc < 4; ++cc) {
          acc[rr][cc] += av[rr].x * bv[cc].x;
          acc[rr][cc] += av[rr].y * bv[cc].y;
          acc[rr][cc] += av[rr].z * bv[cc].z;
          acc[rr][cc] += av[rr].w * bv[cc].w;
        }
    }
  }
  // epilogue: write dist + fused round-1 phase A (comp == identity)
  unsigned long long rowbest[4] = {~0ull, ~0ull, ~0ull, ~0ull};
#pragma unroll
  for (int rr = 0; rr < 4; ++rr) {
    const int i = i0 + ty + 16 * rr;
    const float sqi = sq[i];
#pragma unroll
    for (int cc = 0; cc < 4; ++cc) {
      const int j = j0 + tx + 16 * cc;
      const float d2 = sqi + sq[j] - 2.f * acc[rr][cc];
      const float d = sqrtf(fmaxf(d2, 0.f) + 1e-12f);
      dist[i * 1024 + j] = d;
      if (j != i) {
        const int lo = i < j ? i : j;
        const int hi = i + j - lo;
        const unsigned long long key =
            ((unsigned long long)__float_as_uint(d) << 32)
          | (unsigned long long)((lo << 10) | hi);
        if (key < rowbest[rr]) rowbest[rr] = key;
      }
    }
  }
#pragma unroll
  for (int rr = 0; rr < 4; ++rr) {
    unsigned long long best = rowbest[rr];
#pragma unroll
    for (int off = 8; off; off >>= 1) {      // reduce across the 16-lane tx group
      const unsigned int blo = __shfl_xor((unsigned int)best, off);
      const unsigned int bhi = __shfl_xor((unsigned int)(best >> 32), off);
      const unsigned long long o = ((unsigned long long)bhi << 32) | blo;
      if (o < best) best = o;
    }
    if (tx == 0) atomicMin(&cmin_g[i0 + ty + 16 * rr], best);
  }
  __threadfence();
  if (t == 0) sred[1] = atomicAdd(&ctrl[8 + 15], 1);
  __syncthreads();
  if (sred[1] != 255) return;
  // last-arriving block: round-1 phase B with identity comp
  for (int v = t; v < 1024; v += 256) scomp[v] = v;
  __syncthreads();
  phase_b(scomp, cmin_l, pnew, sred, cmin_g, comp_g, deaths, &ctrl[0], &ctrl[1]);
}

__global__ __launch_bounds__(256) void round_kernel(const float* __restrict__ dist,
                                                    int* __restrict__ comp_g,
                                                    unsigned long long* __restrict__ cmin_g,
                                                    float* __restrict__ deaths,
                                                    int* __restrict__ ctrl,
                                                    int r) {
  __shared__ int scomp[1024];
  __shared__ unsigned long long cmin_l[1024];
  __shared__ int pnew[1024];
  __shared__ int sred[2];
  const int t = threadIdx.x;
  if (t == 0) sred[0] = ctrl[1];             // ncomp from previous round
  __syncthreads();
  if (sred[0] == 1) return;                  // converged: launch-cost only
  for (int v = t; v < 1024; v += 256) scomp[v] = comp_g[v];
  __syncthreads();
  // ---- phase A: one row per wave ----
  const int lane = t & 63;
  const int i = blockIdx.x * 4 + (t >> 6);
  const int ci = scomp[i];
  const float* row = dist + i * 1024;
  unsigned long long best = ~0ull;
#pragma unroll
  for (int k = 0; k < 4; ++k) {
    const int j0 = lane * 4 + k * 256;
    const float4 d4 = *(const float4*)(row + j0);
    const int4 c4 = *(const int4*)(&scomp[j0]);
    const float dv[4] = {d4.x, d4.y, d4.z, d4.w};
    const int cv[4] = {c4.x, c4.y, c4.z, c4.w};
#pragma unroll
    for (int c = 0; c < 4; ++c) {
      if (cv[c] != ci) {
        const int j = j0 + c;
        const int lo = i < j ? i : j;
        const int hi = i + j - lo;
        const unsigned long long key =
            ((unsigned long long)__float_as_uint(dv[c]) << 32)
          | (unsigned long long)((lo << 10) | hi);
        if (key < best) best = key;
      }
    }
  }
#pragma unroll
  for (int off = 32; off; off >>= 1) {
    const unsigned int blo = __shfl_xor((unsigned int)best, off);
    const unsigned int bhi = __shfl_xor((unsigned int)(best >> 32), off);
    const unsigned long long o = ((unsigned long long)bhi << 32) | blo;
    if (o < best) best = o;
  }
  if (lane == 0) atomicMin(&cmin_g[ci], best);
  __threadfence();
  if (t == 0) sred[1] = atomicAdd(&ctrl[8 + r], 1);
  __syncthreads();
  if (sred[1] != 255) return;
  // last-arriving block: phase B
  phase_b(scomp, cmin_l, pnew, sred, cmin_g, comp_g, deaths, &ctrl[0], &ctrl[1]);
}

__global__ __launch_bounds__(1024) void sil_final_kernel(const float* __restrict__ deaths,
                                                         const float* __restrict__ partials,
                                                         float* __restrict__ out) {
  __shared__ float dsh[1023];
  __shared__ float sacc[1024];
  __shared__ float red[48];
  const int t = threadIdx.x;
  float lmax = 0.f, lsum = 0.f;
  if (t < 1023) {
    const float v = deaths[t];
    dsh[t] = v;
    lmax = v;
    lsum = v;
  }
#pragma unroll
  for (int off = 32; off; off >>= 1) {
    lmax = fmaxf(lmax, __shfl_xor(lmax, off));
    lsum += __shfl_xor(lsum, off);
  }
  if ((t & 63) == 0) { red[t >> 6] = lmax; red[16 + (t >> 6)] = lsum; }
  __syncthreads();
  float tmax = 0.f, wsum = 0.f;
#pragma unroll
  for (int w = 0; w < 16; ++w) { tmax = fmaxf(tmax, red[w]); wsum += red[16 + w]; }
  // tent sum: thread t = grid point (t>>2), j-chunk (t&3)
  const int g = t >> 2, c = t & 3;
  const float tt = (float)g * (1.0f / 255.0f) * tmax;
  const int jbeg = c * 256;
  const int jend = (c == 3) ? 1023 : jbeg + 256;
  float acc = 0.f;
  for (int j = jbeg; j < jend; ++j) {
    const float dj = dsh[j];
    acc += dj * fmaxf(fminf(tt, dj - tt), 0.f);
  }
  sacc[t] = acc;
  __syncthreads();
  float phi = 0.f;
  if (t < 256)
    phi = (sacc[4 * t] + sacc[4 * t + 1] + sacc[4 * t + 2] + sacc[4 * t + 3])
        / (wsum + 1e-12f);
  float rs = partials[t];
  float ks = partials[1024 + t];
#pragma unroll
  for (int off = 32; off; off >>= 1) {
    phi += __shfl_xor(phi, off);
    rs += __shfl_xor(rs, off);
    ks += __shfl_xor(ks, off);
  }
  __syncthreads();
  if ((t & 63) == 0) { red[t >> 6] = phi; red[16 + (t >> 6)] = rs; red[32 + (t >> 6)] = ks; }
  __syncthreads();
  if (t == 0) {
    float ph = 0.f, rr = 0.f, kk = 0.f;
#pragma unroll
    for (int w = 0; w < 16; ++w) { ph += red[w]; rr += red[16 + w]; kk += red[32 + w]; }
    const float topo = ph * (1.f / 256.f);
    const float recon = rr * (1.f / 16777216.f);
    const float kl = -0.5f * kk * (1.f / 262144.f);
    const float total = recon + 0.1f * kl + 0.5f * topo;
    out[0] = (float)__float2bfloat16(total);
    out[1] = (float)__float2bfloat16(recon);
    out[2] = (float)__float2bfloat16(kl);
    out[3] = (float)__float2bfloat16(topo);
  }
}

extern "C" void kernel_launch(void* const* d_in, const int* in_sizes, int n_in,
                              void* d_out, int out_size, void* d_ws, size_t ws_size,
                              hipStream_t stream) {
  const float* rx = (const float*)d_in[0];
  const float* x  = (const float*)d_in[1];
  const float* mu = (const float*)d_in[2];
  const float* lv = (const float*)d_in[3];
  const float* z  = (const float*)d_in[4];

  float* wsf = (float*)d_ws;
  float* partials = wsf;                                   // [0..2047]
  float* sq       = wsf + 2048;                            // [2048..3071]
  int*   ctrl     = (int*)(wsf + 3072);                    // [0]=cnt [1]=ncomp [8..23]=done
  float* deaths   = wsf + 3104;                            // 1023 floats
  unsigned long long* cmin_g = (unsigned long long*)(wsf + 4160); // u64[1024]
  int*   comp     = (int*)(wsf + 6208);                    // int[1024]
  float* dist     = wsf + 8192;                            // 4 MB
  float* out      = (float*)d_out;

  losses_kernel<<<NBLK, 512, 0, stream>>>((const float4*)rx, (const float4*)x,
                                          (const float4*)mu, (const float4*)lv,
                                          z, partials, sq, ctrl, cmin_g);
  dist_kernel<<<256, 256, 0, stream>>>(z, sq, dist, ctrl, cmin_g, comp, deaths);
  for (int r = 1; r < 10; ++r)
    round_kernel<<<256, 256, 0, stream>>>(dist, comp, cmin_g, deaths, ctrl, r);
  sil_final_kernel<<<1, 1024, 0, stream>>>(deaths, partials, out);
}

// Round 3
// 229.854 us; speedup vs baseline: 1.6962x; 1.1780x over previous
//
#include <hip/hip_runtime.h>
#include <hip/hip_bf16.h>
#include <math.h>

// ---------------------------------------------------------------------------
// B=1024, D_DATA=16384, D_LAT=256, N_GRID=256. Inputs f32.
// d_out = f32 slots; harness reads high u16 of each slot as bf16 -> store
// (float)__float2bfloat16(v) (proven R6).
//
// Structure (3 launches):
//   losses_kernel : 1024x512, contiguous per-block chunks + unroll x4 (R2
//                   showed VGPR=16 / 2-loads-in-flight latency bound), recon/kl
//                   partials + row norms sq + init cmin buf0/buf1.
//   dist_kernel   : 256x256, dist tiles (diagonal = 0 -> doubles as barrier
//                   counters) + fused Boruvka round-0 phase A (atomicMin with
//                   read-filter into cmin buf0).
//   mst_kernel    : PERSISTENT, 64 blocks x 256 threads. comp in LDS per
//                   block; phase B REDUNDANT per block (deterministic) so the
//                   only cross-block traffic is cmin + a 64-arrival LLC-atomic
//                   barrier (1 per round; NOT CG grid.sync - R1 showed that
//                   costs 25-30us). cmin buffers rotate mod 3 (reset slice of
//                   buf[(r-1)%3] after passing barrier r: all blocks finished
//                   phase B of r-1 by then; next write is phase A of r+2).
//                   Early exit at ncomp==1 (uniform across blocks). Block 0
//                   records deaths in LDS and runs silhouette + final tail.
//
// ws layout (floats):
//   [0..2047]    cmin buf0 (u64[1024])   - round 0 (init by losses)
//   [2048..4095] cmin buf1 (u64[1024])   - round 1 (init by losses)
//   [4096..6143] cmin buf2 (u64[1024])   - round 2 (init by mst start);
//                sq OVERLAYS [4096..5119] (dead after dist_kernel, buf2 first
//                written in round 2 -> after all blocks passed barrier 1)
//   [6144..8191] partials (recon 1024 | kl 1024)
//   [8192..]     dist 1024x1024 (4 MB); diag(r,r) r=1..9 = barrier counters
//                (never consumed as distances: phase A skips comp[j]==comp[i])
// ---------------------------------------------------------------------------

#define NBLK 1024
#define PBLK 64

__device__ __forceinline__ float sub2(const float4 a, const float4 b) {
  const float dx = a.x - b.x, dy = a.y - b.y, dz = a.z - b.z, dw = a.w - b.w;
  return dx * dx + dy * dy + dz * dz + dw * dw;
}

__global__ __launch_bounds__(512) void losses_kernel(const float4* __restrict__ rx,
                                                     const float4* __restrict__ x,
                                                     const float4* __restrict__ mu,
                                                     const float4* __restrict__ lv,
                                                     const float* __restrict__ z,
                                                     float* __restrict__ partials,
                                                     float* __restrict__ sq,
                                                     unsigned long long* __restrict__ cmin01) {
  const int t = threadIdx.x;
  const int b = blockIdx.x;
  if (b == 0) {                       // init cmin buf0+buf1 for this iteration
    for (int v = t; v < 2048; v += 512) cmin01[v] = ~0ull;
  }
  // recon: contiguous 4096-float4 chunk per block, unroll x4 (8 loads in flight)
  const int base = b * 4096 + t;
  float rs = 0.f;
#pragma unroll
  for (int k = 0; k < 2; ++k) {
    const int i0 = base + k * 2048;
    const float4 a0 = rx[i0],        c0 = x[i0];
    const float4 a1 = rx[i0 + 512],  c1 = x[i0 + 512];
    const float4 a2 = rx[i0 + 1024], c2 = x[i0 + 1024];
    const float4 a3 = rx[i0 + 1536], c3 = x[i0 + 1536];
    rs += sub2(a0, c0) + sub2(a1, c1) + sub2(a2, c2) + sub2(a3, c3);
  }
  // kl: one float4 per thread for first 128 blocks
  float ks = 0.f;
  const int gid = b * 512 + t;
  if (gid < 65536) {
    const float4 m = mu[gid], l = lv[gid];
    ks += 1.f + l.x - m.x * m.x - __expf(l.x);
    ks += 1.f + l.y - m.y * m.y - __expf(l.y);
    ks += 1.f + l.z - m.z * m.z - __expf(l.z);
    ks += 1.f + l.w - m.w * m.w - __expf(l.w);
  }
#pragma unroll
  for (int off = 32; off; off >>= 1) {
    rs += __shfl_xor(rs, off);
    ks += __shfl_xor(ks, off);
  }
  __shared__ float red[16];
  if ((t & 63) == 0) { red[t >> 6] = rs; red[8 + (t >> 6)] = ks; }
  __syncthreads();
  if (t == 0) {
    float a = 0.f, c = 0.f;
#pragma unroll
    for (int w = 0; w < 8; ++w) { a += red[w]; c += red[8 + w]; }
    partials[b] = a;
    partials[NBLK + b] = c;
  }
  // sq: blocks 0..127, 8 rows each (one wave per row)
  if (b < 128) {
    const int lane = t & 63;
    const int row = b * 8 + (t >> 6);
    const float4 v = ((const float4*)(z + row * 256))[lane];
    float s = v.x * v.x + v.y * v.y + v.z * v.z + v.w * v.w;
#pragma unroll
    for (int off = 32; off; off >>= 1) s += __shfl_xor(s, off);
    if (lane == 0) sq[row] = s;
  }
}

__global__ __launch_bounds__(256) void dist_kernel(const float* __restrict__ z,
                                                   const float* __restrict__ sq,
                                                   float* __restrict__ dist,
                                                   unsigned long long* __restrict__ cmin0) {
  __shared__ float A[64][68];
  __shared__ float Bs[64][68];
  const int i0 = (blockIdx.x >> 4) * 64, j0 = (blockIdx.x & 15) * 64;
  const int t = threadIdx.x;
  const int tx = t & 15;
  const int ty = t >> 4;
  float acc[4][4] = {};
  for (int k0 = 0; k0 < 256; k0 += 64) {
    __syncthreads();
#pragma unroll
    for (int it = 0; it < 4; ++it) {
      int lin = it * 256 + t;
      int row = lin >> 4, q = lin & 15;
      *(float4*)&A[row][q * 4]  = *(const float4*)(z + (i0 + row) * 256 + k0 + q * 4);
      *(float4*)&Bs[row][q * 4] = *(const float4*)(z + (j0 + row) * 256 + k0 + q * 4);
    }
    __syncthreads();
#pragma unroll 4
    for (int k = 0; k < 64; k += 4) {
      float4 av[4], bv[4];
#pragma unroll
      for (int rr = 0; rr < 4; ++rr) av[rr] = *(const float4*)&A[ty + 16 * rr][k];
#pragma unroll
      for (int cc = 0; cc < 4; ++cc) bv[cc] = *(const float4*)&Bs[tx + 16 * cc][k];
#pragma unroll
      for (int rr = 0; rr < 4; ++rr)
#pragma unroll
        for (int cc = 0; cc < 4; ++cc) {
          acc[rr][cc] += av[rr].x * bv[cc].x;
          acc[rr][cc] += av[rr].y * bv[cc].y;
          acc[rr][cc] += av[rr].z * bv[cc].z;
          acc[rr][cc] += av[rr].w * bv[cc].w;
        }
    }
  }
  // epilogue: dist write (diag = 0 -> pre-zeroed barrier counters) + fused
  // round-0 phase A (identity comp) with read-filtered atomicMin
  unsigned long long rowbest[4] = {~0ull, ~0ull, ~0ull, ~0ull};
#pragma unroll
  for (int rr = 0; rr < 4; ++rr) {
    const int i = i0 + ty + 16 * rr;
    const float sqi = sq[i];
#pragma unroll
    for (int cc = 0; cc < 4; ++cc) {
      const int j = j0 + tx + 16 * cc;
      const float d2 = sqi + sq[j] - 2.f * acc[rr][cc];
      const float d = sqrtf(fmaxf(d2, 0.f) + 1e-12f);
      dist[i * 1024 + j] = (j == i) ? 0.f : d;
      if (j != i) {
        const int lo = i < j ? i : j;
        const int hi = i + j - lo;
        const unsigned long long key =
            ((unsigned long long)__float_as_uint(d) << 32)
          | (unsigned long long)((lo << 10) | hi);
        if (key < rowbest[rr]) rowbest[rr] = key;
      }
    }
  }
#pragma unroll
  for (int rr = 0; rr < 4; ++rr) {
    unsigned long long best = rowbest[rr];
#pragma unroll
    for (int off = 8; off; off >>= 1) {
      const unsigned int blo = __shfl_xor((unsigned int)best, off);
      const unsigned int bhi = __shfl_xor((unsigned int)(best >> 32), off);
      const unsigned long long o = ((unsigned long long)bhi << 32) | blo;
      if (o < best) best = o;
    }
    if (tx == 0) {
      unsigned long long* p = &cmin0[i0 + ty + 16 * rr];
      const unsigned long long cur =
          __hip_atomic_load(p, __ATOMIC_RELAXED, __HIP_MEMORY_SCOPE_AGENT);
      if (best < cur) atomicMin(p, best);
    }
  }
}

// Redundant phase B (every block, deterministic): read settled cmin via
// agent-scope atomic loads (bypass L1), merge, pointer-double, root-walk.
// Returns new component count. Block 0 records deaths into LDS.
__device__ __forceinline__ int phase_b_dev(const unsigned long long* __restrict__ cbuf,
                                           int* scomp, unsigned long long* cl,
                                           int* pnew, int* sred,
                                           bool record, float* sdeaths, int* scnt) {
  const int t = threadIdx.x;
  for (int v = t; v < 1024; v += 256)
    cl[v] = __hip_atomic_load(&cbuf[v], __ATOMIC_RELAXED, __HIP_MEMORY_SCOPE_AGENT);
  if (t == 0) sred[0] = 0;
  __syncthreads();
  for (int v = t; v < 1024; v += 256) {
    int parent = scomp[v];
    if (parent == v) {                         // root
      const unsigned long long key = cl[v];
      if (key != ~0ull) {
        const int lo = (int)((key >> 10) & 1023), hi = (int)(key & 1023);
        const int clo = scomp[lo], chi = scomp[hi];
        const int other = (clo == v) ? chi : clo;
        const bool mutual = (cl[other] == key);
        if (record && (!mutual || v < other)) {
          const int pos = atomicAdd(scnt, 1);
          sdeaths[pos] = __uint_as_float((unsigned int)(key >> 32));
        }
        parent = (mutual && v < other) ? v : other;
      }
    }
    pnew[v] = parent;
  }
  __syncthreads();
#pragma unroll
  for (int it = 0; it < 2; ++it) {
    int q0 = pnew[pnew[t]];
    int q1 = pnew[pnew[t + 256]];
    int q2 = pnew[pnew[t + 512]];
    int q3 = pnew[pnew[t + 768]];
    __syncthreads();
    pnew[t] = q0; pnew[t + 256] = q1; pnew[t + 512] = q2; pnew[t + 768] = q3;
    __syncthreads();
  }
  int nroots = 0;
#pragma unroll
  for (int q = 0; q < 4; ++q) {
    const int v = t + q * 256;
    int p = pnew[v];
    while (p != pnew[p]) p = pnew[p];
    scomp[v] = p;
    if (p == v) ++nroots;
  }
  atomicAdd(&sred[0], nroots);
  __syncthreads();
  return sred[0];
}

__global__ __launch_bounds__(256) void mst_kernel(const float* __restrict__ dist,
                                                  unsigned long long* __restrict__ cminb,
                                                  const float* __restrict__ partials,
                                                  float* __restrict__ out) {
  __shared__ int scomp[1024];
  __shared__ int pnew[1024];
  __shared__ unsigned long long cl[1024];
  __shared__ float sdeaths[1023];
  __shared__ int sred[2];              // [0] root count, [1] death count
  __shared__ float redf[12];
  const int t = threadIdx.x;
  const int b = blockIdx.x;
  const bool rec = (b == 0);

  for (int v = t; v < 1024; v += 256) scomp[v] = v;
  if (t == 0) sred[1] = 0;
  if (t < 16)                          // init buf2 slice (sq overlay is dead)
    __hip_atomic_store(&cminb[2048 + b * 16 + t], ~0ull,
                       __ATOMIC_RELAXED, __HIP_MEMORY_SCOPE_AGENT);
  __syncthreads();

  int ncomp = phase_b_dev(cminb, scomp, cl, pnew, sred, rec, sdeaths, &sred[1]);

  const int lane = t & 63;
  const int w = t >> 6;
  for (int r = 1; r < 10 && ncomp > 1; ++r) {
    unsigned long long* cbuf = cminb + (r % 3) * 1024;
    // ---- phase A: 16 rows per block (4 waves x 4 rows) ----
#pragma unroll
    for (int q = 0; q < 4; ++q) {
      const int i = b * 16 + w * 4 + q;
      const int ci = scomp[i];
      const float* row = dist + i * 1024;
      unsigned long long best = ~0ull;
#pragma unroll
      for (int k = 0; k < 4; ++k) {
        const int j0 = lane * 4 + k * 256;
        const float4 d4 = *(const float4*)(row + j0);
        const int4 c4 = *(const int4*)(&scomp[j0]);
        const float dv[4] = {d4.x, d4.y, d4.z, d4.w};
        const int cv[4] = {c4.x, c4.y, c4.z, c4.w};
#pragma unroll
        for (int c = 0; c < 4; ++c) {
          if (cv[c] != ci) {
            const int j = j0 + c;
            const int lo = i < j ? i : j;
            const int hi = i + j - lo;
            const unsigned long long key =
                ((unsigned long long)__float_as_uint(dv[c]) << 32)
              | (unsigned long long)((lo << 10) | hi);
            if (key < best) best = key;
          }
        }
      }
#pragma unroll
      for (int off = 32; off; off >>= 1) {
        const unsigned int blo = __shfl_xor((unsigned int)best, off);
        const unsigned int bhi = __shfl_xor((unsigned int)(best >> 32), off);
        const unsigned long long o = ((unsigned long long)bhi << 32) | blo;
        if (o < best) best = o;
      }
      if (lane == 0 && best != ~0ull) {
        const unsigned long long cur =
            __hip_atomic_load(&cbuf[ci], __ATOMIC_RELAXED, __HIP_MEMORY_SCOPE_AGENT);
        if (best < cur) atomicMin(&cbuf[ci], best);   // read-filter: low contention
      }
    }
    // ---- barrier r: 64-arrival counter in dist diagonal (LLC atomics) ----
    int* ctrp = (int*)(dist + (size_t)r * 1025);
    __syncthreads();
    if (t == 0) {
      __hip_atomic_fetch_add(ctrp, 1, __ATOMIC_ACQ_REL, __HIP_MEMORY_SCOPE_AGENT);
      while (__hip_atomic_load(ctrp, __ATOMIC_ACQUIRE, __HIP_MEMORY_SCOPE_AGENT) < PBLK)
        __builtin_amdgcn_s_sleep(2);
    }
    __syncthreads();
    // reset previous round's buffer slice (reused in round r+2; race-free:
    // all blocks passed barrier r => all finished phase B of r-1)
    if (t < 16)
      __hip_atomic_store(&cminb[((r - 1) % 3) * 1024 + b * 16 + t], ~0ull,
                         __ATOMIC_RELAXED, __HIP_MEMORY_SCOPE_AGENT);
    ncomp = phase_b_dev(cbuf, scomp, cl, pnew, sred, rec, sdeaths, &sred[1]);
  }

  // ---------------- tail: silhouette + final (block 0 only) ----------------
  if (b != 0) return;
  float lmax = 0.f, lsum = 0.f;
  for (int v = t; v < 1023; v += 256) {
    const float d = sdeaths[v];
    lmax = fmaxf(lmax, d);
    lsum += d;
  }
#pragma unroll
  for (int off = 32; off; off >>= 1) {
    lmax = fmaxf(lmax, __shfl_xor(lmax, off));
    lsum += __shfl_xor(lsum, off);
  }
  if ((t & 63) == 0) { redf[t >> 6] = lmax; redf[4 + (t >> 6)] = lsum; }
  __syncthreads();
  const float tmax = fmaxf(fmaxf(redf[0], redf[1]), fmaxf(redf[2], redf[3]));
  const float wsum = redf[4] + redf[5] + redf[6] + redf[7];
  const float tt = (float)t * (1.0f / 255.0f) * tmax;
  float acc = 0.f;
  for (int j = 0; j < 1023; ++j) {
    const float dj = sdeaths[j];
    acc += dj * fmaxf(fminf(tt, dj - tt), 0.f);
  }
  float phi = acc / (wsum + 1e-12f);
  float rs = 0.f, ks = 0.f;
  for (int v = t; v < 1024; v += 256) { rs += partials[v]; ks += partials[1024 + v]; }
#pragma unroll
  for (int off = 32; off; off >>= 1) {
    phi += __shfl_xor(phi, off);
    rs += __shfl_xor(rs, off);
    ks += __shfl_xor(ks, off);
  }
  __syncthreads();
  if ((t & 63) == 0) { redf[t >> 6] = phi; redf[4 + (t >> 6)] = rs; redf[8 + (t >> 6)] = ks; }
  __syncthreads();
  if (t == 0) {
    const float topo = (redf[0] + redf[1] + redf[2] + redf[3]) * (1.f / 256.f);
    const float recon = (redf[4] + redf[5] + redf[6] + redf[7]) * (1.f / 16777216.f);
    const float kl = -0.5f * (redf[8] + redf[9] + redf[10] + redf[11]) * (1.f / 262144.f);
    const float total = recon + 0.1f * kl + 0.5f * topo;
    out[0] = (float)__float2bfloat16(total);
    out[1] = (float)__float2bfloat16(recon);
    out[2] = (float)__float2bfloat16(kl);
    out[3] = (float)__float2bfloat16(topo);
  }
}

extern "C" void kernel_launch(void* const* d_in, const int* in_sizes, int n_in,
                              void* d_out, int out_size, void* d_ws, size_t ws_size,
                              hipStream_t stream) {
  const float* rx = (const float*)d_in[0];
  const float* x  = (const float*)d_in[1];
  const float* mu = (const float*)d_in[2];
  const float* lv = (const float*)d_in[3];
  const float* z  = (const float*)d_in[4];

  float* wsf = (float*)d_ws;
  unsigned long long* cminb = (unsigned long long*)wsf;    // 3 x u64[1024]
  float* sq       = wsf + 4096;                            // overlays cmin buf2
  float* partials = wsf + 6144;                            // 2048 floats
  float* dist     = wsf + 8192;                            // 4 MB
  float* out      = (float*)d_out;

  losses_kernel<<<NBLK, 512, 0, stream>>>((const float4*)rx, (const float4*)x,
                                          (const float4*)mu, (const float4*)lv,
                                          z, partials, sq, cminb);
  dist_kernel<<<256, 256, 0, stream>>>(z, sq, dist, cminb);
  mst_kernel<<<PBLK, 256, 0, stream>>>(dist, cminb, partials, out);
}